// Round 7
// baseline (385.877 us; speedup 1.0000x reference)
//
#include <hip/hip_runtime.h>
#include <math.h>

namespace {
constexpr int kB = 256;
constexpr int kD = 128;
constexpr int kN = 500000;
constexpr int kKC = 2049;             // K + 1
constexpr int kNPair = kB * kKC;      // 524544
constexpr float kTInv = 1.0f / 0.07f;
constexpr float kMom = 0.5f;
constexpr int kRB = 256;              // reduction grid size
constexpr long long kM = (long long)kN * kD;    // 64,000,000 floats per bank
constexpr long long kTot = 2 * kM;
// mixed kernel geometry: per 8 blocks, 5 copy + 3 dots
constexpr int kBlocks = 2048;
constexpr int kCopyBlocks = kBlocks / 8 * 5;          // 1280
constexpr int kDotsBlocks = kBlocks / 8 * 3;          // 768
constexpr long long kCopyThreads = (long long)kCopyBlocks * 256;  // 327680
constexpr long long kDotsWaves = (long long)kDotsBlocks * 4;      // 3072
}

// ---------- mixed kernel: copy-role blocks stream the banks at HBM BW;
// dots-role blocks gather pair rows (latency-bound, low BW) in the shadow.
// Copy: out[1+g] = S[g] for S = concat(mem1, mem2), aligned float4 stores,
// each output float4 rebuilt from two adjacent source float4s (the duplicate
// line reads hit L1/L2; HBM fetches each line once).
// Dots: one (b,k) pair per wave iteration; lanes 0-31 handle bank1·teacher
// (-> e2), lanes 32-63 handle bank2·student (-> e1); float4 row loads,
// 5-level half-wave butterfly; 3-deep pipeline (cidx 2-ahead, row/emb
// 1-ahead, issued before the current compute's wait -> stays in flight).
__global__ __launch_bounds__(256) void mixed_kernel(
    const float* __restrict__ mem1, const float* __restrict__ mem2,
    const float* __restrict__ teacher, const float* __restrict__ student,
    const int* __restrict__ cidx,
    float* __restrict__ out, float* __restrict__ e2, float* __restrict__ e1)
{
    const int grp = blockIdx.x & 7;
    if (grp < 5) {
        // ---- copy role ----
        const long long NV4 = (kTot + 1) / 4;     // 32,000,000 float4 stores
        const long long KS  = kM / 4;             // bank boundary float4 index
        const float4* m1v = reinterpret_cast<const float4*>(mem1);
        const float4* m2v = reinterpret_cast<const float4*>(mem2);
        float4* ov = reinterpret_cast<float4*>(out);
        long long copyRank = (long long)(blockIdx.x >> 3) * 5 + grp;
        for (long long k = copyRank * 256 + threadIdx.x; k < NV4; k += kCopyThreads) {
            if (k == 0) {
                out[1] = mem1[0]; out[2] = mem1[1]; out[3] = mem1[2];
                out[kTot] = mem2[kM - 1];         // final tail element
                continue;
            }
            float4 r;
            if (k < KS) {
                float4 a = m1v[k - 1];
                float4 b = m1v[k];
                r = make_float4(a.w, b.x, b.y, b.z);
            } else if (k == KS) {
                r = make_float4(mem1[kM - 1], mem2[0], mem2[1], mem2[2]);
            } else {
                float4 a = m2v[k - KS - 1];
                float4 b = m2v[k - KS];
                r = make_float4(a.w, b.x, b.y, b.z);
            }
            ov[k] = r;
        }
    } else {
        // ---- dots role ----
        const int lane = threadIdx.x & 63;
        const int half = lane >> 5;       // 0: mem1·teacher->e2 ; 1: mem2·student->e1
        const int c = lane & 31;
        const float4* bank4 = reinterpret_cast<const float4*>(half ? mem2 : mem1);
        const float4* emb4  = reinterpret_cast<const float4*>(half ? student : teacher);
        float* ep = half ? e1 : e2;

        long long dotsRank = (long long)(blockIdx.x >> 3) * 3 + (grp - 5);
        long long wid = dotsRank * 4 + (threadIdx.x >> 6);

        long long p0 = wid;
        if (p0 >= kNPair) return;
        // stage 0: row+emb for p0; cidx for p0+stride
        int r0 = cidx[p0];
        float4 rv = bank4[(long long)r0 * 32 + c];
        float4 ev = emb4[(long long)((unsigned)p0 / (unsigned)kKC) * 32 + c];
        int rn = (p0 + kDotsWaves < kNPair) ? cidx[p0 + kDotsWaves] : 0;

        for (long long p = p0; p < kNPair; p += kDotsWaves) {
            long long pn  = p + kDotsWaves;
            long long pn2 = p + 2 * kDotsWaves;
            int rn2 = (pn2 < kNPair) ? cidx[pn2] : 0;
            float4 rvn = make_float4(0.f, 0.f, 0.f, 0.f);
            float4 evn = rvn;
            if (pn < kNPair) {
                rvn = bank4[(long long)rn * 32 + c];
                evn = emb4[(long long)((unsigned)pn / (unsigned)kKC) * 32 + c];
            }
            // compute current (waits only rv/ev; rvn/evn/rn2 stay in flight)
            float d = rv.x * ev.x + rv.y * ev.y + rv.z * ev.z + rv.w * ev.w;
            d += __shfl_xor(d, 16);
            d += __shfl_xor(d, 8);
            d += __shfl_xor(d, 4);
            d += __shfl_xor(d, 2);
            d += __shfl_xor(d, 1);
            if (c == 0) ep[p] = __expf(d * kTInv);
            rv = rvn; ev = evn; rn = rn2;
        }
    }
}

// ---------- loss chain ----------

__global__ __launch_bounds__(256) void sums_kernel(
    const float* __restrict__ e2, const float* __restrict__ e1,
    float* __restrict__ p2, float* __restrict__ p1)
{
    __shared__ float s2[256], s1[256];
    float a2 = 0.f, a1 = 0.f;
    for (int i = blockIdx.x * 256 + threadIdx.x; i < kNPair; i += 256 * kRB) {
        a2 += e2[i];
        a1 += e1[i];
    }
    s2[threadIdx.x] = a2; s1[threadIdx.x] = a1;
    __syncthreads();
    for (int st = 128; st > 0; st >>= 1) {
        if ((int)threadIdx.x < st) {
            s2[threadIdx.x] += s2[threadIdx.x + st];
            s1[threadIdx.x] += s1[threadIdx.x + st];
        }
        __syncthreads();
    }
    if (threadIdx.x == 0) { p2[blockIdx.x] = s2[0]; p1[blockIdx.x] = s1[0]; }
}

__global__ __launch_bounds__(256) void z_kernel(
    const float* __restrict__ p2, const float* __restrict__ p1, float* __restrict__ z)
{
    __shared__ float s2[256], s1[256];
    s2[threadIdx.x] = p2[threadIdx.x];
    s1[threadIdx.x] = p1[threadIdx.x];
    __syncthreads();
    for (int st = 128; st > 0; st >>= 1) {
        if ((int)threadIdx.x < st) {
            s2[threadIdx.x] += s2[threadIdx.x + st];
            s1[threadIdx.x] += s1[threadIdx.x + st];
        }
        __syncthreads();
    }
    if (threadIdx.x == 0) {
        const float scale = (float)kN / (float)kNPair;
        z[0] = s2[0] * scale;   // z_v2
        z[1] = s1[0] * scale;   // z_v1
    }
}

__global__ __launch_bounds__(256) void lossp_kernel(
    const float* __restrict__ e2, const float* __restrict__ e1,
    const float* __restrict__ z, float* __restrict__ lp)
{
    const float mpn = 2048.0f / 500000.0f;
    const float noise = mpn + 1e-7f;
    const float iz2 = 1.0f / z[0];
    const float iz1 = 1.0f / z[1];
    float acc = 0.f;
    for (int i = blockIdx.x * 256 + threadIdx.x; i < kNPair; i += 256 * kRB) {
        int k = i % kKC;
        float x2 = e2[i] * iz2;
        float x1 = e1[i] * iz1;
        if (k == 0) {
            acc += __logf(x2 / (x2 + noise)) + __logf(x1 / (x1 + noise));
        } else {
            acc += __logf(mpn / (x2 + noise)) + __logf(mpn / (x1 + noise));
        }
    }
    __shared__ float s[256];
    s[threadIdx.x] = acc;
    __syncthreads();
    for (int st = 128; st > 0; st >>= 1) {
        if ((int)threadIdx.x < st) s[threadIdx.x] += s[threadIdx.x + st];
        __syncthreads();
    }
    if (threadIdx.x == 0) lp[blockIdx.x] = s[0];
}

__global__ __launch_bounds__(256) void final_kernel(
    const float* __restrict__ lp, float* __restrict__ out)
{
    __shared__ float s[256];
    s[threadIdx.x] = lp[threadIdx.x];
    __syncthreads();
    for (int st = 128; st > 0; st >>= 1) {
        if ((int)threadIdx.x < st) s[threadIdx.x] += s[threadIdx.x + st];
        __syncthreads();
    }
    if (threadIdx.x == 0) out[0] = -s[0] / (float)kB;
}

// ---------- momentum update of the 256 pos rows ----------

__global__ __launch_bounds__(64) void update_kernel(
    const float* __restrict__ mem1, const float* __restrict__ mem2,
    const float* __restrict__ student, const float* __restrict__ teacher,
    const int* __restrict__ pos_idx,
    float* __restrict__ out1, float* __restrict__ out2)
{
    int b = blockIdx.x;
    int lane = threadIdx.x;
    int p = pos_idx[b];
    for (int b2 = b + 1; b2 < kB; ++b2)
        if (pos_idx[b2] == p) return;   // a later write wins
    long long row = (long long)p * kD;
    float2 m1 = *reinterpret_cast<const float2*>(mem1 + row + lane * 2);
    float2 m2 = *reinterpret_cast<const float2*>(mem2 + row + lane * 2);
    float2 sv = *reinterpret_cast<const float2*>(student + b * kD + lane * 2);
    float2 tv = *reinterpret_cast<const float2*>(teacher + b * kD + lane * 2);
    // v1 pairs with student, v2 pairs with teacher (per reference)
    float2 l1 = make_float2(m1.x * kMom + sv.x * (1.f - kMom),
                            m1.y * kMom + sv.y * (1.f - kMom));
    float2 l2 = make_float2(m2.x * kMom + tv.x * (1.f - kMom),
                            m2.y * kMom + tv.y * (1.f - kMom));
    float n1 = l1.x * l1.x + l1.y * l1.y;
    float n2 = l2.x * l2.x + l2.y * l2.y;
    #pragma unroll
    for (int off = 32; off > 0; off >>= 1) {
        n1 += __shfl_xor(n1, off);
        n2 += __shfl_xor(n2, off);
    }
    float i1 = 1.0f / sqrtf(n1);
    float i2 = 1.0f / sqrtf(n2);
    out1[row + lane * 2]     = l1.x * i1;
    out1[row + lane * 2 + 1] = l1.y * i1;
    out2[row + lane * 2]     = l2.x * i2;
    out2[row + lane * 2 + 1] = l2.y * i2;
}

extern "C" void kernel_launch(void* const* d_in, const int* in_sizes, int n_in,
                              void* d_out, int out_size, void* d_ws, size_t ws_size,
                              hipStream_t stream) {
    const float* student = (const float*)d_in[0];
    const float* teacher = (const float*)d_in[1];
    const float* mem1    = (const float*)d_in[2];
    const float* mem2    = (const float*)d_in[3];
    const int*   pos_idx = (const int*)d_in[4];
    const int*   cidx    = (const int*)d_in[5];

    float* out  = (float*)d_out;
    float* out1 = out + 1;                // new_memory_v1
    float* out2 = out + 1 + kM;           // new_memory_v2

    float* ws = (float*)d_ws;
    float* e2 = ws;                       // kNPair exps (mem1 . teacher)
    float* e1 = e2 + kNPair;              // kNPair exps (mem2 . student)
    float* p2 = e1 + kNPair;              // kRB
    float* p1 = p2 + kRB;                 // kRB
    float* zz = p1 + kRB;                 // 2
    float* lp = zz + 2;                   // kRB

    mixed_kernel<<<kBlocks, 256, 0, stream>>>(mem1, mem2, teacher, student,
                                              cidx, out, e2, e1);
    sums_kernel<<<kRB, 256, 0, stream>>>(e2, e1, p2, p1);
    z_kernel<<<1, 256, 0, stream>>>(p2, p1, zz);
    lossp_kernel<<<kRB, 256, 0, stream>>>(e2, e1, zz, lp);
    final_kernel<<<1, 256, 0, stream>>>(lp, out);
    update_kernel<<<kB, 64, 0, stream>>>(mem1, mem2, student, teacher, pos_idx, out1, out2);
}